// Round 2
// baseline (351.559 us; speedup 1.0000x reference)
//
#include <hip/hip_runtime.h>

// ---------------------------------------------------------------------------
// BCNet: v_=relu(v@Wv^T+bv); q_=relu(q@Wq^T+bq); out[b,h,v,q]=sum_k h[h,k]*v_*q_ + hbias[h]
// Shapes: B=32, NV=512, NQ=128, V_DIM=2048, Q_DIM=1024, HK=1536, H_OUT=8
// ---------------------------------------------------------------------------

typedef _Float16 h8 __attribute__((ext_vector_type(8)));
typedef float f32x4 __attribute__((ext_vector_type(4)));

#define B_   32
#define NV_  512
#define NQ_  128
#define VD_  2048
#define QD_  1024
#define HK_  1536
#define HO_  8

#define SBAR() asm volatile("s_barrier" ::: "memory")
#define WAITV(n) asm volatile("s_waitcnt vmcnt(" #n ")" ::: "memory")

__device__ __forceinline__ void gload_lds16(const void* g, void* l) {
  __builtin_amdgcn_global_load_lds(
      (const __attribute__((address_space(1))) void*)g,
      (__attribute__((address_space(3))) void*)l, 16, 0, 0);
}

// ---------------------------------------------------------------------------
// f32 -> f16 conversion, 8 elements/thread
// ---------------------------------------------------------------------------
__global__ __launch_bounds__(256) void cvt_f32_f16(const float* __restrict__ in,
                                                   _Float16* __restrict__ out,
                                                   int n8) {
  int i = blockIdx.x * blockDim.x + threadIdx.x;
  if (i >= n8) return;
  const float4* p = (const float4*)in;
  float4 a = p[i * 2];
  float4 b = p[i * 2 + 1];
  h8 o;
  o[0] = (_Float16)a.x; o[1] = (_Float16)a.y; o[2] = (_Float16)a.z; o[3] = (_Float16)a.w;
  o[4] = (_Float16)b.x; o[5] = (_Float16)b.y; o[6] = (_Float16)b.z; o[7] = (_Float16)b.w;
  ((h8*)out)[i] = o;
}

// ---------------------------------------------------------------------------
// Phase-interleaved GEMM: out[m][n] = relu(sum_k A[m][k]*Bw[n][k] + bias[n])
// Tile 256x128, BK=64 (2 kk-slabs of 32), 8 waves (4M x 2N), per-wave 64x64.
// LDS: A slabs [2buf][2kk][256][32] f16, B slabs [2][2][128][32] f16 = 96 KB.
// Swizzle: 16B slot ^= (row&3); staged via pre-swizzled global source
// (linear gload_lds dest), read with the same XOR -> conflict-free ds_read_b128.
// Phase: {stage 3 loads for tile t+1 | 8 ds_read | s_barrier | setprio+16 MFMA |
//         vmcnt(3) | s_barrier}. Counted vmcnt keeps loads in flight across
// barriers (T3+T4); raw asm barriers avoid compiler's vmcnt(0) drain.
// ---------------------------------------------------------------------------
template <int KTOT>
__global__ __launch_bounds__(512, 2) void gemm8p_relu_f16(
    const _Float16* __restrict__ A, const _Float16* __restrict__ Bw,
    const float* __restrict__ bias, _Float16* __restrict__ out, int N) {
  __shared__ __align__(16) _Float16 Asl[2][2][256 * 32];
  __shared__ __align__(16) _Float16 Bsl[2][2][128 * 32];

  const int t = threadIdx.x;
  const int lane = t & 63;
  const int wave = t >> 6;   // 0..7
  const int wm = wave >> 1;  // 0..3
  const int wn = wave & 1;   // 0..1

  // bijective XCD swizzle (grid size divisible by 8 for all our launches)
  const int nwg = gridDim.x * gridDim.y;
  const int flat = blockIdx.y * gridDim.x + blockIdx.x;
  const int swz = (flat & 7) * (nwg >> 3) + (flat >> 3);
  const int brow = (swz % gridDim.x) * 256;
  const int bcol = (swz / gridDim.x) * 128;

  // staging thread mapping: thread covers 16B slot (t&3) of row (t>>2)
  const int srow = t >> 2;
  const int slogS = (t & 3) ^ (srow & 3);  // inverse-swizzled source slot

  constexpr int NT = KTOT / 64;
  f32x4 acc[4][4] = {};

  auto stageA = [&](int tile, int kk) {
    const _Float16* src = A + (size_t)(brow + srow) * KTOT + tile * 64 + kk * 32 + slogS * 8;
    gload_lds16(src, &Asl[tile & 1][kk][t * 8]);
    gload_lds16(src + (size_t)128 * KTOT, &Asl[tile & 1][kk][t * 8 + 4096]);
  };
  auto stageB = [&](int tile, int kk) {
    gload_lds16(Bw + (size_t)(bcol + srow) * KTOT + tile * 64 + kk * 32 + slogS * 8,
                &Bsl[tile & 1][kk][t * 8]);
  };
  auto phase = [&](int tile, int kk, bool dostage) {
    if (dostage) { stageA(tile + 1, kk); stageB(tile + 1, kk); }
    const int b = tile & 1;
    h8 af[4], bf[4];
#pragma unroll
    for (int m = 0; m < 4; ++m) {
      const int row = wm * 64 + m * 16 + (lane & 15);
      const int slot = (lane >> 4) ^ (row & 3);
      af[m] = *(const h8*)&Asl[b][kk][row * 32 + slot * 8];
    }
#pragma unroll
    for (int n = 0; n < 4; ++n) {
      const int row = wn * 64 + n * 16 + (lane & 15);
      const int slot = (lane >> 4) ^ (row & 3);
      bf[n] = *(const h8*)&Bsl[b][kk][row * 32 + slot * 8];
    }
    SBAR();
    __builtin_amdgcn_s_setprio(1);
#pragma unroll
    for (int m = 0; m < 4; ++m)
#pragma unroll
      for (int n = 0; n < 4; ++n)
        acc[m][n] = __builtin_amdgcn_mfma_f32_16x16x32_f16(af[m], bf[n], acc[m][n], 0, 0, 0);
    __builtin_amdgcn_s_setprio(0);
  };

  // prologue: stage tile 0 fully (6 loads); wait oldest 3 (kk=0 slab)
  stageA(0, 0); stageB(0, 0);
  stageA(0, 1); stageB(0, 1);
  WAITV(3);
  SBAR();

  for (int tile = 0; tile < NT - 1; ++tile) {
    phase(tile, 0, true);
    WAITV(3);
    SBAR();
    phase(tile, 1, true);
    WAITV(3);
    SBAR();
  }
  // peeled tail: no more staging; drain remaining kk=1 slab loads
  phase(NT - 1, 0, false);
  WAITV(0);
  SBAR();
  phase(NT - 1, 1, false);

#pragma unroll
  for (int m = 0; m < 4; ++m)
#pragma unroll
    for (int n = 0; n < 4; ++n) {
      const int col = bcol + wn * 64 + n * 16 + (lane & 15);
      const float bb = bias[col];
#pragma unroll
      for (int r = 0; r < 4; ++r) {
        const int row = brow + wm * 64 + m * 16 + (lane >> 4) * 4 + r;
        float val = acc[m][n][r] + bb;
        val = val > 0.f ? val : 0.f;
        out[(size_t)row * N + col] = (_Float16)val;
      }
    }
}

// ---------------------------------------------------------------------------
// Bilinear: out[b,h,v,q] = sum_k vh[b,v,k] * (h16[h,k]*qh[b,q,k]) + hbias[h]
// (unchanged from round 1 — validated)
// ---------------------------------------------------------------------------
__global__ __launch_bounds__(256) void bilinear_f16(
    const _Float16* __restrict__ vh, const _Float16* __restrict__ qh,
    const _Float16* __restrict__ h16, const float* __restrict__ hbias,
    float* __restrict__ out) {
  __shared__ __align__(16) _Float16 As[128 * 64];
  __shared__ __align__(16) _Float16 Bs[128 * 64];

  const int lane = threadIdx.x & 63;
  const int wave = threadIdx.x >> 6;
  const int wm = wave >> 1, wn = wave & 1;
  const int t = threadIdx.x;
  const int mt = blockIdx.x;
  const int h = blockIdx.y;
  const int b = blockIdx.z;

  const _Float16* Ab = vh + ((size_t)b * NV_ + mt * 128) * HK_;
  const _Float16* Qb = qh + (size_t)b * NQ_ * HK_;
  const _Float16* Hb = h16 + h * HK_;

  const int sr = lane >> 3;
  const int sk = (lane & 7) * 8;

  f32x4 acc[4][4] = {};

  for (int kt = 0; kt < HK_ / 64; ++kt) {
    __syncthreads();
#pragma unroll
    for (int i = 0; i < 4; ++i) {
      const int c = wave * 4 + i;
      gload_lds16(Ab + (size_t)(c * 8 + sr) * HK_ + kt * 64 + sk,
                  &As[c * 512 + lane * 8]);
    }
    const h8 hv = *(const h8*)&Hb[kt * 64 + (t & 7) * 8];
#pragma unroll
    for (int r = 0; r < 4; ++r) {
      const int slot = r * 256 + t;
      const int row = slot >> 3;
      const h8 qv = *(const h8*)&Qb[(size_t)row * HK_ + kt * 64 + (t & 7) * 8];
      h8 o = qv * hv;
      *(h8*)&Bs[slot * 8] = o;
    }
    __syncthreads();
#pragma unroll
    for (int kk = 0; kk < 2; ++kk) {
      h8 af[4], bf[4];
#pragma unroll
      for (int m = 0; m < 4; ++m)
        af[m] = *(const h8*)&As[(wm * 64 + m * 16 + (lane & 15)) * 64 + kk * 32 + (lane >> 4) * 8];
#pragma unroll
      for (int n = 0; n < 4; ++n)
        bf[n] = *(const h8*)&Bs[(wn * 64 + n * 16 + (lane & 15)) * 64 + kk * 32 + (lane >> 4) * 8];
#pragma unroll
      for (int m = 0; m < 4; ++m)
#pragma unroll
        for (int n = 0; n < 4; ++n)
          acc[m][n] = __builtin_amdgcn_mfma_f32_16x16x32_f16(af[m], bf[n], acc[m][n], 0, 0, 0);
    }
  }

  const float bb = hbias[h];
  float* O = out + (((size_t)b * HO_ + h) * NV_ + (size_t)mt * 128) * NQ_;
#pragma unroll
  for (int m = 0; m < 4; ++m)
#pragma unroll
    for (int n = 0; n < 4; ++n)
#pragma unroll
      for (int r = 0; r < 4; ++r) {
        const int row = wm * 64 + m * 16 + (lane >> 4) * 4 + r;
        const int col = wn * 64 + n * 16 + (lane & 15);
        O[(size_t)row * NQ_ + col] = acc[m][n][r] + bb;
      }
}

// ---------------------------------------------------------------------------
// Workspace layout (bytes): v16@0 (67,108,864) q16@67108864 (8,388,608)
// Wv16@75497472 (6,291,456) Wq16@81788928 (3,145,728) vh@84934656 (50,331,648)
// qh@135266304 (12,582,912) h16@147849216 (24,576) total 147,873,792
// ---------------------------------------------------------------------------
extern "C" void kernel_launch(void* const* d_in, const int* in_sizes, int n_in,
                              void* d_out, int out_size, void* d_ws,
                              size_t ws_size, hipStream_t stream) {
  const float* v = (const float*)d_in[0];
  const float* q = (const float*)d_in[1];
  const float* Wv = (const float*)d_in[2];
  const float* bv = (const float*)d_in[3];
  const float* Wq = (const float*)d_in[4];
  const float* bq = (const float*)d_in[5];
  const float* hmat = (const float*)d_in[6];
  const float* hbias = (const float*)d_in[7];

  if (ws_size < 147873792u) return;

  char* ws = (char*)d_ws;
  _Float16* v16 = (_Float16*)(ws);
  _Float16* q16 = (_Float16*)(ws + 67108864);
  _Float16* Wv16 = (_Float16*)(ws + 75497472);
  _Float16* Wq16 = (_Float16*)(ws + 81788928);
  _Float16* vh = (_Float16*)(ws + 84934656);
  _Float16* qh = (_Float16*)(ws + 135266304);
  _Float16* h16 = (_Float16*)(ws + 147849216);

  cvt_f32_f16<<<dim3((33554432 / 8 + 255) / 256), 256, 0, stream>>>(v, v16, 33554432 / 8);
  cvt_f32_f16<<<dim3((4194304 / 8 + 255) / 256), 256, 0, stream>>>(q, q16, 4194304 / 8);
  cvt_f32_f16<<<dim3((3145728 / 8 + 255) / 256), 256, 0, stream>>>(Wv, Wv16, 3145728 / 8);
  cvt_f32_f16<<<dim3((1572864 / 8 + 255) / 256), 256, 0, stream>>>(Wq, Wq16, 1572864 / 8);
  cvt_f32_f16<<<dim3((12288 / 8 + 255) / 256), 256, 0, stream>>>(hmat, h16, 12288 / 8);

  // v_ = relu(v @ Wv^T + bv): M=16384, N=1536, K=2048 -> 64x12 = 768 blocks
  gemm8p_relu_f16<VD_><<<dim3(16384 / 256, HK_ / 128), 512, 0, stream>>>(v16, Wv16, bv, vh, HK_);
  // q_ = relu(q @ Wq^T + bq): M=4096, N=1536, K=1024 -> 16x12 = 192 blocks
  gemm8p_relu_f16<QD_><<<dim3(4096 / 256, HK_ / 128), 512, 0, stream>>>(q16, Wq16, bq, qh, HK_);

  bilinear_f16<<<dim3(NV_ / 128, HO_, B_), 256, 0, stream>>>(vh, qh, h16, hbias, (float*)d_out);
}

// Round 3
// 314.711 us; speedup vs baseline: 1.1171x; 1.1171x over previous
//
#include <hip/hip_runtime.h>

// ---------------------------------------------------------------------------
// BCNet: v_=relu(v@Wv^T+bv); q_=relu(q@Wq^T+bq); out[b,h,v,q]=sum_k h[h,k]*v_*q_ + hbias[h]
// Shapes: B=32, NV=512, NQ=128, V_DIM=2048, Q_DIM=1024, HK=1536, H_OUT=8
//
// Round-3 structure: 256x128 tile, BK=64, 8 waves (4Mx2N, 64x64 each),
// TRIPLE-buffered LDS K-tiles (144KB), depth-2-tile counted-vmcnt prefetch,
// st_16x32 swizzle (byte bit5 ^= bit9) on 128B LDS rows, no XCD swizzle.
// ---------------------------------------------------------------------------

typedef _Float16 h8 __attribute__((ext_vector_type(8)));
typedef float f32x4 __attribute__((ext_vector_type(4)));

#define B_   32
#define NV_  512
#define NQ_  128
#define VD_  2048
#define QD_  1024
#define HK_  1536
#define HO_  8

#define SBAR()   asm volatile("s_barrier" ::: "memory")
#define WAITV(n) asm volatile("s_waitcnt vmcnt(" #n ")" ::: "memory")
#define LGKM0()  asm volatile("s_waitcnt lgkmcnt(0)" ::: "memory")

__device__ __forceinline__ void gload_lds16(const void* g, void* l) {
  __builtin_amdgcn_global_load_lds(
      (const __attribute__((address_space(1))) void*)g,
      (__attribute__((address_space(3))) void*)l, 16, 0, 0);
}

// ---------------------------------------------------------------------------
// f32 -> f16 conversion, 8 elements/thread
// ---------------------------------------------------------------------------
__global__ __launch_bounds__(256) void cvt_f32_f16(const float* __restrict__ in,
                                                   _Float16* __restrict__ out,
                                                   int n8) {
  int i = blockIdx.x * blockDim.x + threadIdx.x;
  if (i >= n8) return;
  const float4* p = (const float4*)in;
  float4 a = p[i * 2];
  float4 b = p[i * 2 + 1];
  h8 o;
  o[0] = (_Float16)a.x; o[1] = (_Float16)a.y; o[2] = (_Float16)a.z; o[3] = (_Float16)a.w;
  o[4] = (_Float16)b.x; o[5] = (_Float16)b.y; o[6] = (_Float16)b.z; o[7] = (_Float16)b.w;
  ((h8*)out)[i] = o;
}

// ---------------------------------------------------------------------------
// GEMM: out = relu(A @ Bw^T + bias), f16 in/out. A: MxK, Bw: NxK (K-major).
// Grid: (N/128, M/256) — bcol fastest for L3 lockstep over A.
// ---------------------------------------------------------------------------
template <int KTOT>
__global__ __launch_bounds__(512, 2) void gemm_p3_relu_f16(
    const _Float16* __restrict__ A, const _Float16* __restrict__ Bw,
    const float* __restrict__ bias, _Float16* __restrict__ out, int N) {
  __shared__ __align__(16) _Float16 As[3][256 * 64];
  __shared__ __align__(16) _Float16 Bs[3][128 * 64];

  const int t = threadIdx.x;
  const int lane = t & 63;
  const int wave = t >> 6;
  const int wm = wave >> 1, wn = wave & 1;
  const int bcol = blockIdx.x * 128;
  const int brow = blockIdx.y * 256;

  // staging map: thread t covers 16B unit t of each 8KB chunk (64 rows x 128B).
  // st_16x32 swizzle is an involution (byte bit5 ^= bit9), row-preserving:
  // stage LINEAR into LDS from the pre-swizzled global column.
  const int srow = t >> 3;                                 // row 0..63 in chunk
  const int scol = ((t & 7) * 8) ^ (((t >> 5) & 1) << 4);  // swizzled f16 col

  constexpr int NT = KTOT / 64;
  f32x4 acc[4][4] = {};

  auto stage_half = [&](int kt, int hh) {  // 3 loads: 2 A-chunks + 1 B-chunk
    const int bi = kt % 3;
    const _Float16* sa = A + (size_t)(brow + hh * 128 + srow) * KTOT + kt * 64 + scol;
    gload_lds16(sa, &As[bi][hh * 8192 + t * 8]);
    gload_lds16(sa + (size_t)64 * KTOT, &As[bi][hh * 8192 + 4096 + t * 8]);
    const _Float16* sb = Bw + (size_t)(bcol + hh * 64 + srow) * KTOT + kt * 64 + scol;
    gload_lds16(sb, &Bs[bi][hh * 4096 + t * 8]);
  };

  auto phase = [&](int kt, int kk) {  // 8 ds_read_b128 + 16 MFMA
    const int bi = kt % 3;
    h8 af[4], bf[4];
#pragma unroll
    for (int m = 0; m < 4; ++m) {
      const int row = wm * 64 + m * 16 + (lane & 15);
      const int idx = (row * 64 + kk * 32 + (lane >> 4) * 8) ^ ((row & 4) << 2);
      af[m] = *(const h8*)&As[bi][idx];
    }
#pragma unroll
    for (int n = 0; n < 4; ++n) {
      const int row = wn * 64 + n * 16 + (lane & 15);
      const int idx = (row * 64 + kk * 32 + (lane >> 4) * 8) ^ ((row & 4) << 2);
      bf[n] = *(const h8*)&Bs[bi][idx];
    }
    __builtin_amdgcn_s_setprio(1);
#pragma unroll
    for (int m = 0; m < 4; ++m)
#pragma unroll
      for (int n = 0; n < 4; ++n)
        acc[m][n] = __builtin_amdgcn_mfma_f32_16x16x32_f16(af[m], bf[n], acc[m][n], 0, 0, 0);
    __builtin_amdgcn_s_setprio(0);
  };

  // prologue: tiles 0 and 1 in flight (12 loads); drain tile 0 (oldest 6)
  stage_half(0, 0); stage_half(0, 1);
  stage_half(1, 0); stage_half(1, 1);
  WAITV(6); SBAR();

  for (int kt = 0; kt < NT - 2; ++kt) {
    stage_half(kt + 2, 0);   // buffer (kt+2)%3: readers done 2 barriers ago
    phase(kt, 0);
    stage_half(kt + 2, 1);
    phase(kt, 1);
    WAITV(6); SBAR();        // drain tile kt+1's 6; keep kt+2's 6 in flight
  }
  phase(NT - 2, 0); phase(NT - 2, 1);
  WAITV(0); SBAR();
  phase(NT - 1, 0); phase(NT - 1, 1);

#pragma unroll
  for (int m = 0; m < 4; ++m)
#pragma unroll
    for (int n = 0; n < 4; ++n) {
      const int col = bcol + wn * 64 + n * 16 + (lane & 15);
      const float bb = bias[col];
#pragma unroll
      for (int r = 0; r < 4; ++r) {
        const int row = brow + wm * 64 + m * 16 + (lane >> 4) * 4 + r;
        float val = acc[m][n][r] + bb;
        val = val > 0.f ? val : 0.f;
        out[(size_t)row * N + col] = (_Float16)val;
      }
    }
}

// ---------------------------------------------------------------------------
// Bilinear: out[b,h,v,q] = sum_k vh[b,v,k]*(h16[h,k]*qh[b,q,k]) + hbias[h]
// Same pipelined structure; A-side (vh) via gload_lds, B-side (qh*h) via
// T14 reg-stage: loads issued 2 tiles early, scaled ds_write 1 tile later.
// Grid: (NV/256, B*HO).
// ---------------------------------------------------------------------------
__global__ __launch_bounds__(512, 2) void bilinear_p3_f16(
    const _Float16* __restrict__ vh, const _Float16* __restrict__ qh,
    const _Float16* __restrict__ h16, const float* __restrict__ hbias,
    float* __restrict__ out) {
  __shared__ __align__(16) _Float16 As[3][256 * 64];
  __shared__ __align__(16) _Float16 Bs[3][128 * 64];

  const int t = threadIdx.x;
  const int lane = t & 63;
  const int wave = t >> 6;
  const int wm = wave >> 1, wn = wave & 1;
  const int mt = blockIdx.x;       // 0..1
  const int bh = blockIdx.y;       // 0..255 = b*8+h
  const int h = bh & 7;

  const _Float16* Ab = vh + ((size_t)(bh >> 3) * NV_ + mt * 256) * HK_;
  const _Float16* Qb = qh + (size_t)(bh >> 3) * NQ_ * HK_;
  const _Float16* Hb = h16 + (size_t)h * HK_;

  const int srow = t >> 3;
  const int scol = ((t & 7) * 8) ^ (((t >> 5) & 1) << 4);

  constexpr int NT = HK_ / 64;     // 24 (even)
  f32x4 acc[4][4] = {};

  auto stage_halfA = [&](int kt, int hh) {  // 2 gload_lds (A only)
    const int bi = kt % 3;
    const _Float16* sa = Ab + (size_t)(hh * 128 + srow) * HK_ + kt * 64 + scol;
    gload_lds16(sa, &As[bi][hh * 8192 + t * 8]);
    gload_lds16(sa + (size_t)64 * HK_, &As[bi][hh * 8192 + 4096 + t * 8]);
  };

  // B-side reg stage: thread covers 16B units t and t+512 (same k-offset,
  // rows r and r+64) -> 2 q-loads + 1 shared h-load per tile.
  const int qr0 = t >> 3;              // 0..63
  const int qk = (t & 7) * 8;          // k offset in tile
  auto qload = [&](int kt, h8& qv0, h8& qv1, h8& hv) {
    qv0 = *(const h8*)&Qb[(size_t)qr0 * HK_ + kt * 64 + qk];
    qv1 = *(const h8*)&Qb[(size_t)(qr0 + 64) * HK_ + kt * 64 + qk];
    hv = *(const h8*)&Hb[kt * 64 + qk];
  };
  auto dswrite = [&](int kt, h8 qv0, h8 qv1, h8 hv) {
    const int bi = kt % 3;
    const int i0 = (qr0 * 64 + qk) ^ ((qr0 & 4) << 2);
    *(h8*)&Bs[bi][i0] = qv0 * hv;
    const int r1 = qr0 + 64;
    const int i1 = (r1 * 64 + qk) ^ ((r1 & 4) << 2);
    *(h8*)&Bs[bi][i1] = qv1 * hv;
  };

  auto phase = [&](int kt, int kk) {
    const int bi = kt % 3;
    h8 af[4], bf[4];
#pragma unroll
    for (int m = 0; m < 4; ++m) {
      const int row = wm * 64 + m * 16 + (lane & 15);
      const int idx = (row * 64 + kk * 32 + (lane >> 4) * 8) ^ ((row & 4) << 2);
      af[m] = *(const h8*)&As[bi][idx];
    }
#pragma unroll
    for (int n = 0; n < 4; ++n) {
      const int row = wn * 64 + n * 16 + (lane & 15);
      const int idx = (row * 64 + kk * 32 + (lane >> 4) * 8) ^ ((row & 4) << 2);
      bf[n] = *(const h8*)&Bs[bi][idx];
    }
    __builtin_amdgcn_s_setprio(1);
#pragma unroll
    for (int m = 0; m < 4; ++m)
#pragma unroll
      for (int n = 0; n < 4; ++n)
        acc[m][n] = __builtin_amdgcn_mfma_f32_16x16x32_f16(af[m], bf[n], acc[m][n], 0, 0, 0);
    __builtin_amdgcn_s_setprio(0);
  };

  h8 qv0A, qv1A, hvA, qv0B, qv1B, hvB;

  // prologue: tiles 0,1
  qload(0, qv0A, qv1A, hvA);
  stage_halfA(0, 0); stage_halfA(0, 1);
  qload(1, qv0B, qv1B, hvB);
  stage_halfA(1, 0); stage_halfA(1, 1);
  dswrite(0, qv0A, qv1A, hvA);   // compiler vmcnt drains qv(0) (+older)
  dswrite(1, qv0B, qv1B, hvB);   // drains qv(1) -> A(0) drained too (older)
  WAITV(4); LGKM0(); SBAR();     // belt+suspenders: only A(1) may remain

  for (int kt = 0; kt < NT - 2; kt += 2) {
    // even step: regs A hold tile kt+2, regs B hold tile kt+1
    qload(kt + 2, qv0A, qv1A, hvA);
    stage_halfA(kt + 2, 0);
    phase(kt, 0);
    stage_halfA(kt + 2, 1);
    phase(kt, 1);
    dswrite(kt + 1, qv0B, qv1B, hvB);
    WAITV(7); LGKM0(); SBAR();   // drain A(kt+1) (oldest); keep kt+2 in flight

    // odd step
    qload(kt + 3, qv0B, qv1B, hvB);
    stage_halfA(kt + 3, 0);
    phase(kt + 1, 0);
    stage_halfA(kt + 3, 1);
    phase(kt + 1, 1);
    dswrite(kt + 2, qv0A, qv1A, hvA);
    WAITV(7); LGKM0(); SBAR();
  }
  // tail (NT even): tiles NT-2, NT-1 staged; B(NT-1) regs live in set B
  phase(NT - 2, 0); phase(NT - 2, 1);
  dswrite(NT - 1, qv0B, qv1B, hvB);
  WAITV(0); LGKM0(); SBAR();
  phase(NT - 1, 0); phase(NT - 1, 1);

  const float bb = hbias[h];
  float* O = out + ((size_t)bh * NV_ + (size_t)mt * 256) * NQ_;
#pragma unroll
  for (int m = 0; m < 4; ++m)
#pragma unroll
    for (int n = 0; n < 4; ++n)
#pragma unroll
      for (int r = 0; r < 4; ++r) {
        const int row = wm * 64 + m * 16 + (lane >> 4) * 4 + r;
        const int col = wn * 64 + n * 16 + (lane & 15);
        O[(size_t)row * NQ_ + col] = acc[m][n][r] + bb;
      }
}

// ---------------------------------------------------------------------------
// Workspace layout (bytes): v16@0 (67,108,864) q16@67108864 (8,388,608)
// Wv16@75497472 (6,291,456) Wq16@81788928 (3,145,728) vh@84934656 (50,331,648)
// qh@135266304 (12,582,912) h16@147849216 (24,576) total 147,873,792
// ---------------------------------------------------------------------------
extern "C" void kernel_launch(void* const* d_in, const int* in_sizes, int n_in,
                              void* d_out, int out_size, void* d_ws,
                              size_t ws_size, hipStream_t stream) {
  const float* v = (const float*)d_in[0];
  const float* q = (const float*)d_in[1];
  const float* Wv = (const float*)d_in[2];
  const float* bv = (const float*)d_in[3];
  const float* Wq = (const float*)d_in[4];
  const float* bq = (const float*)d_in[5];
  const float* hmat = (const float*)d_in[6];
  const float* hbias = (const float*)d_in[7];

  if (ws_size < 147873792u) return;

  char* ws = (char*)d_ws;
  _Float16* v16 = (_Float16*)(ws);
  _Float16* q16 = (_Float16*)(ws + 67108864);
  _Float16* Wv16 = (_Float16*)(ws + 75497472);
  _Float16* Wq16 = (_Float16*)(ws + 81788928);
  _Float16* vh = (_Float16*)(ws + 84934656);
  _Float16* qh = (_Float16*)(ws + 135266304);
  _Float16* h16 = (_Float16*)(ws + 147849216);

  cvt_f32_f16<<<dim3((33554432 / 8 + 255) / 256), 256, 0, stream>>>(v, v16, 33554432 / 8);
  cvt_f32_f16<<<dim3((4194304 / 8 + 255) / 256), 256, 0, stream>>>(q, q16, 4194304 / 8);
  cvt_f32_f16<<<dim3((3145728 / 8 + 255) / 256), 256, 0, stream>>>(Wv, Wv16, 3145728 / 8);
  cvt_f32_f16<<<dim3((1572864 / 8 + 255) / 256), 256, 0, stream>>>(Wq, Wq16, 1572864 / 8);
  cvt_f32_f16<<<dim3((12288 / 8 + 255) / 256), 256, 0, stream>>>(hmat, h16, 12288 / 8);

  // v_ = relu(v @ Wv^T + bv): M=16384, N=1536, K=2048 -> grid (12, 64)
  gemm_p3_relu_f16<VD_><<<dim3(HK_ / 128, 16384 / 256), 512, 0, stream>>>(v16, Wv16, bv, vh, HK_);
  // q_ = relu(q @ Wq^T + bq): M=4096, N=1536, K=1024 -> grid (12, 16)
  gemm_p3_relu_f16<QD_><<<dim3(HK_ / 128, 4096 / 256), 512, 0, stream>>>(q16, Wq16, bq, qh, HK_);

  // logits: grid (2, 256)
  bilinear_p3_f16<<<dim3(NV_ / 256, B_ * HO_), 512, 0, stream>>>(vh, qh, h16, hbias, (float*)d_out);
}

// Round 4
// 306.853 us; speedup vs baseline: 1.1457x; 1.0256x over previous
//
#include <hip/hip_runtime.h>

// ---------------------------------------------------------------------------
// BCNet: v_=relu(v@Wv^T+bv); q_=relu(q@Wq^T+bq); out[b,h,v,q]=sum_k h[h,k]*v_*q_ + hbias[h]
// Round 4: per-wave 128x64 MFMA intensity (24 ds_read -> 64 MFMA per K-tile),
// 64B LDS rows with slot^=(row>>1)&3 swizzle (2-way = free), counted vmcnt,
// XCD-grouped block remaps.
// ---------------------------------------------------------------------------

typedef _Float16 h8 __attribute__((ext_vector_type(8)));
typedef float f32x4 __attribute__((ext_vector_type(4)));

#define B_   32
#define NV_  512
#define NQ_  128
#define VD_  2048
#define QD_  1024
#define HK_  1536
#define HO_  8

#define SBAR()   asm volatile("s_barrier" ::: "memory")
#define WAITV(n) asm volatile("s_waitcnt vmcnt(" #n ")" ::: "memory")
#define LGKM0()  do { asm volatile("s_waitcnt lgkmcnt(0)" ::: "memory"); \
                      __builtin_amdgcn_sched_barrier(0); } while (0)

__device__ __forceinline__ void gload_lds16(const void* g, void* l) {
  __builtin_amdgcn_global_load_lds(
      (const __attribute__((address_space(1))) void*)g,
      (__attribute__((address_space(3))) void*)l, 16, 0, 0);
}

// ---------------------------------------------------------------------------
// f32 -> f16 conversion, 8 elements/thread
// ---------------------------------------------------------------------------
__global__ __launch_bounds__(256) void cvt_f32_f16(const float* __restrict__ in,
                                                   _Float16* __restrict__ out,
                                                   int n8) {
  int i = blockIdx.x * blockDim.x + threadIdx.x;
  if (i >= n8) return;
  const float4* p = (const float4*)in;
  float4 a = p[i * 2];
  float4 b = p[i * 2 + 1];
  h8 o;
  o[0] = (_Float16)a.x; o[1] = (_Float16)a.y; o[2] = (_Float16)a.z; o[3] = (_Float16)a.w;
  o[4] = (_Float16)b.x; o[5] = (_Float16)b.y; o[6] = (_Float16)b.z; o[7] = (_Float16)b.w;
  ((h8*)out)[i] = o;
}

// ---------------------------------------------------------------------------
// GEMM: out = relu(A @ Bw^T + bias), f16 in/out. A: MxK, Bw: NxK (K-major).
// BM=BN=256, BK=64 (2 kk-slabs of 32), 8 waves (2wm x 4wn), per-wave 128x64.
// LDS [2dbuf][2kk][256 rows x 32 k] for A and B = 128 KB.
// 4 phases per K-tile; WAITV(4) at end of ph1 and ph3 (kk-half drains).
// ---------------------------------------------------------------------------
template <int KTOT>
__global__ __launch_bounds__(512, 2) void gemm_8p_relu_f16(
    const _Float16* __restrict__ A, const _Float16* __restrict__ Bw,
    const float* __restrict__ bias, _Float16* __restrict__ out, int N) {
  __shared__ __align__(16) _Float16 Asl[2][2][256 * 32];
  __shared__ __align__(16) _Float16 Bsl[2][2][256 * 32];

  const int t = threadIdx.x;
  const int lane = t & 63;
  const int wave = t >> 6;
  const int wm = wave >> 2;  // 0..1
  const int wn = wave & 3;   // 0..3

  // XCD-grouped remap: brow-panel p pinned to xcd p%8; its 6 bcol-blocks
  // run consecutively on that xcd -> A panel served from L2.
  const int flat = blockIdx.y * gridDim.x + blockIdx.x;  // gridDim.x == 6
  const int x8 = flat & 7;
  const int j = flat >> 3;
  const int brow = (x8 + 8 * (j / 6)) * 256;
  const int bcol = (j % 6) * 256;

  // staging: unit = 128 rows x 64B; thread t -> row t>>2, slot t&3 (linear dest).
  // swizzle: physical slot p = logical ^ ((row>>1)&3); dest linear => source
  // column pre-swizzled with the same XOR.
  const int srow = t >> 2;
  const int sdst = t * 8;  // linear LDS element offset within a unit
  const int scol = ((t & 3) ^ ((t >> 3) & 3)) * 8;

  constexpr int NT = KTOT / 64;
  f32x4 acc[8][4] = {};

  auto stgA = [&](int tile, int kk) {
    const int bi = tile & 1;
    const _Float16* s = A + (size_t)(brow + srow) * KTOT + tile * 64 + kk * 32 + scol;
    gload_lds16(s, &Asl[bi][kk][sdst]);
    gload_lds16(s + (size_t)128 * KTOT, &Asl[bi][kk][4096 + sdst]);
  };
  auto stgB = [&](int tile, int kk) {
    const int bi = tile & 1;
    const _Float16* s = Bw + (size_t)(bcol + srow) * KTOT + tile * 64 + kk * 32 + scol;
    gload_lds16(s, &Bsl[bi][kk][sdst]);
    gload_lds16(s + (size_t)128 * KTOT, &Bsl[bi][kk][4096 + sdst]);
  };

  h8 af[4], bf[4];
  auto rdA = [&](int bi, int kk, int mh) {
#pragma unroll
    for (int m = 0; m < 4; ++m) {
      const int row = wm * 128 + mh * 64 + m * 16 + (lane & 15);
      const int p = ((lane >> 4) ^ ((row >> 1) & 3)) * 8;
      af[m] = *(const h8*)&Asl[bi][kk][row * 32 + p];
    }
  };
  auto rdB = [&](int bi, int kk) {
#pragma unroll
    for (int n = 0; n < 4; ++n) {
      const int row = wn * 64 + n * 16 + (lane & 15);
      const int p = ((lane >> 4) ^ ((row >> 1) & 3)) * 8;
      bf[n] = *(const h8*)&Bsl[bi][kk][row * 32 + p];
    }
  };
  auto mfma16 = [&](int mh) {
    __builtin_amdgcn_s_setprio(1);
#pragma unroll
    for (int m = 0; m < 4; ++m)
#pragma unroll
      for (int n = 0; n < 4; ++n)
        acc[mh * 4 + m][n] =
            __builtin_amdgcn_mfma_f32_16x16x32_f16(af[m], bf[n], acc[mh * 4 + m][n], 0, 0, 0);
    __builtin_amdgcn_s_setprio(0);
  };

  // prologue: stage tile 0 (8 loads); drain kk0 halves (oldest 4)
  stgA(0, 0); stgB(0, 0); stgA(0, 1); stgB(0, 1);
  WAITV(4); SBAR();

  for (int tile = 0; tile < NT - 1; ++tile) {
    const int bi = tile & 1;
    // ph0: read kk0 m0-3 + B(kk0); stage A-kk0(t+1)
    rdA(bi, 0, 0); rdB(bi, 0);
    stgA(tile + 1, 0);
    SBAR(); LGKM0(); mfma16(0); SBAR();
    // ph1: read kk0 m4-7; stage B-kk0(t+1); drain kk1(t)
    rdA(bi, 0, 1);
    stgB(tile + 1, 0);
    SBAR(); LGKM0(); mfma16(1);
    WAITV(4); SBAR();
    // ph2: read kk1 m0-3 + B(kk1); stage A-kk1(t+1)
    rdA(bi, 1, 0); rdB(bi, 1);
    stgA(tile + 1, 1);
    SBAR(); LGKM0(); mfma16(0); SBAR();
    // ph3: read kk1 m4-7; stage B-kk1(t+1); drain kk0(t+1)
    rdA(bi, 1, 1);
    stgB(tile + 1, 1);
    SBAR(); LGKM0(); mfma16(1);
    WAITV(4); SBAR();
  }
  {  // tail tile NT-1 (no staging)
    const int bi = (NT - 1) & 1;
    rdA(bi, 0, 0); rdB(bi, 0);
    SBAR(); LGKM0(); mfma16(0); SBAR();
    rdA(bi, 0, 1);
    SBAR(); LGKM0(); mfma16(1);
    WAITV(0); SBAR();
    rdA(bi, 1, 0); rdB(bi, 1);
    SBAR(); LGKM0(); mfma16(0); SBAR();
    rdA(bi, 1, 1);
    SBAR(); LGKM0(); mfma16(1);
  }

  float bb[4];
#pragma unroll
  for (int n = 0; n < 4; ++n) bb[n] = bias[bcol + wn * 64 + n * 16 + (lane & 15)];
#pragma unroll
  for (int mi = 0; mi < 8; ++mi) {
#pragma unroll
    for (int n = 0; n < 4; ++n) {
      const int col = bcol + wn * 64 + n * 16 + (lane & 15);
#pragma unroll
      for (int r = 0; r < 4; ++r) {
        const int row = brow + wm * 128 + mi * 16 + (lane >> 4) * 4 + r;
        float val = acc[mi][n][r] + bb[n];
        out[(size_t)row * N + col] = (_Float16)(val > 0.f ? val : 0.f);
      }
    }
  }
}

// ---------------------------------------------------------------------------
// Bilinear: out[b,h,v,q] = sum_k vh[b,v,k]*(h16[h,k]*qh[b,q,k]) + hbias[h]
// BM=512(=NV), BN=128(=NQ): one block per (b,h), 256 blocks, 8 waves (4x2),
// per-wave 128x64. BK=32 slabs, triple-buffered (123 KB). A via gload_lds,
// B = qh*h reg-staged (h row in LDS). WAITV(5) per slab.
// ---------------------------------------------------------------------------
__global__ __launch_bounds__(512, 2) void bilinear_8p_f16(
    const _Float16* __restrict__ vh, const _Float16* __restrict__ qh,
    const _Float16* __restrict__ h16, const float* __restrict__ hbias,
    float* __restrict__ out) {
  __shared__ __align__(16) _Float16 Asl[3][512 * 32];  // 96 KB
  __shared__ __align__(16) _Float16 Bsl[3][128 * 32];  // 24 KB
  __shared__ __align__(16) _Float16 hl[HK_];           // 3 KB

  const int t = threadIdx.x;
  const int lane = t & 63;
  const int wave = t >> 6;
  const int wm = wave >> 1;  // 0..3
  const int wn = wave & 1;   // 0..1

  // XCD-grouped (b,h) remap: a given b's 8 h-blocks land on one xcd -> vh L2 reuse.
  const int i = blockIdx.x;
  const int b = (i & 7) * 4 + ((i >> 3) & 3);
  const int h = i >> 5;

  const _Float16* Ab = vh + (size_t)b * NV_ * HK_;
  const _Float16* Qb = qh + (size_t)b * NQ_ * HK_;

  if (t < HK_ / 8)
    *(h8*)&hl[t * 8] = *(const h8*)&h16[(size_t)h * HK_ + t * 8];
  __syncthreads();

  const int srow = t >> 2;
  const int sdst = t * 8;
  const int scol = ((t & 3) ^ ((t >> 3) & 3)) * 8;
  const int qrow = t >> 2;                              // 0..127
  const int qs = (t & 3) * 8;                           // logical col
  const int bp = (((t & 3) ^ ((qrow >> 1) & 3)) * 8);   // physical slot

  constexpr int NT = HK_ / 32;  // 48
  f32x4 acc[8][4] = {};

  auto stgA = [&](int s) {
    const int bi = s % 3;
    const _Float16* src = Ab + (size_t)srow * HK_ + s * 32 + scol;
#pragma unroll
    for (int u = 0; u < 4; ++u)
      gload_lds16(src + (size_t)(u * 128) * HK_, &Asl[bi][u * 4096 + sdst]);
  };
  auto qld = [&](int s) { return *(const h8*)&Qb[(size_t)qrow * HK_ + s * 32 + qs]; };
  auto bwr = [&](int s, h8 qv) {
    const h8 hv = *(const h8*)&hl[s * 32 + qs];
    *(h8*)&Bsl[s % 3][qrow * 32 + bp] = qv * hv;
  };

  h8 af[8], bf[4];
  auto rds = [&](int s) {
    const int bi = s % 3;
#pragma unroll
    for (int m = 0; m < 8; ++m) {
      const int row = wm * 128 + m * 16 + (lane & 15);
      const int p = ((lane >> 4) ^ ((row >> 1) & 3)) * 8;
      af[m] = *(const h8*)&Asl[bi][row * 32 + p];
    }
#pragma unroll
    for (int n = 0; n < 4; ++n) {
      const int row = wn * 64 + n * 16 + (lane & 15);
      const int p = ((lane >> 4) ^ ((row >> 1) & 3)) * 8;
      bf[n] = *(const h8*)&Bsl[bi][row * 32 + p];
    }
  };
  auto mfma32 = [&]() {
    __builtin_amdgcn_s_setprio(1);
#pragma unroll
    for (int m = 0; m < 8; ++m)
#pragma unroll
      for (int n = 0; n < 4; ++n)
        acc[m][n] = __builtin_amdgcn_mfma_f32_16x16x32_f16(af[m], bf[n], acc[m][n], 0, 0, 0);
    __builtin_amdgcn_s_setprio(0);
  };

  // prologue: slabs 0,1 in flight; drain slab 0 (oldest 5: qv0 + A0x4)
  h8 qcur = qld(0); stgA(0);
  h8 qnxt = qld(1); stgA(1);
  WAITV(5);
  bwr(0, qcur);
  qcur = qnxt;
  asm volatile("s_waitcnt lgkmcnt(0)" ::: "memory");
  SBAR();

  for (int s = 0; s < NT - 2; ++s) {
    qnxt = qld(s + 2);
    stgA(s + 2);
    rds(s);
    WAITV(5);            // drain slab s+1's {qv, A x4}
    bwr(s + 1, qcur);
    qcur = qnxt;
    LGKM0();
    mfma32();
    SBAR();
  }
  // s = NT-2: nothing new staged; drain everything, write last B
  rds(NT - 2);
  WAITV(0);
  bwr(NT - 1, qcur);
  LGKM0();
  mfma32();
  SBAR();
  // s = NT-1
  rds(NT - 1);
  LGKM0();
  mfma32();

  const float bb = hbias[h];
  float* O = out + ((size_t)b * HO_ + h) * NV_ * NQ_;
#pragma unroll
  for (int m = 0; m < 8; ++m)
#pragma unroll
    for (int n = 0; n < 4; ++n)
#pragma unroll
      for (int r = 0; r < 4; ++r) {
        const int row = wm * 128 + m * 16 + (lane >> 4) * 4 + r;
        const int col = wn * 64 + n * 16 + (lane & 15);
        O[(size_t)row * NQ_ + col] = acc[m][n][r] + bb;
      }
}

// ---------------------------------------------------------------------------
// Workspace layout (bytes): v16@0 (67,108,864) q16@67108864 (8,388,608)
// Wv16@75497472 (6,291,456) Wq16@81788928 (3,145,728) vh@84934656 (50,331,648)
// qh@135266304 (12,582,912) h16@147849216 (24,576) total 147,873,792
// ---------------------------------------------------------------------------
extern "C" void kernel_launch(void* const* d_in, const int* in_sizes, int n_in,
                              void* d_out, int out_size, void* d_ws,
                              size_t ws_size, hipStream_t stream) {
  const float* v = (const float*)d_in[0];
  const float* q = (const float*)d_in[1];
  const float* Wv = (const float*)d_in[2];
  const float* bv = (const float*)d_in[3];
  const float* Wq = (const float*)d_in[4];
  const float* bq = (const float*)d_in[5];
  const float* hmat = (const float*)d_in[6];
  const float* hbias = (const float*)d_in[7];

  if (ws_size < 147873792u) return;

  char* ws = (char*)d_ws;
  _Float16* v16 = (_Float16*)(ws);
  _Float16* q16 = (_Float16*)(ws + 67108864);
  _Float16* Wv16 = (_Float16*)(ws + 75497472);
  _Float16* Wq16 = (_Float16*)(ws + 81788928);
  _Float16* vh = (_Float16*)(ws + 84934656);
  _Float16* qh = (_Float16*)(ws + 135266304);
  _Float16* h16 = (_Float16*)(ws + 147849216);

  cvt_f32_f16<<<dim3((33554432 / 8 + 255) / 256), 256, 0, stream>>>(v, v16, 33554432 / 8);
  cvt_f32_f16<<<dim3((4194304 / 8 + 255) / 256), 256, 0, stream>>>(q, q16, 4194304 / 8);
  cvt_f32_f16<<<dim3((3145728 / 8 + 255) / 256), 256, 0, stream>>>(Wv, Wv16, 3145728 / 8);
  cvt_f32_f16<<<dim3((1572864 / 8 + 255) / 256), 256, 0, stream>>>(Wq, Wq16, 1572864 / 8);
  cvt_f32_f16<<<dim3((12288 / 8 + 255) / 256), 256, 0, stream>>>(hmat, h16, 12288 / 8);

  // v_ = relu(v @ Wv^T + bv): M=16384, N=1536, K=2048 -> grid (6, 64) = 384
  gemm_8p_relu_f16<VD_><<<dim3(HK_ / 256, 16384 / 256), 512, 0, stream>>>(v16, Wv16, bv, vh, HK_);
  // q_ = relu(q @ Wq^T + bq): M=4096, N=1536, K=1024 -> grid (6, 16) = 96
  gemm_8p_relu_f16<QD_><<<dim3(HK_ / 256, 4096 / 256), 512, 0, stream>>>(q16, Wq16, bq, qh, HK_);

  // logits: one block per (b,h) = 256 blocks
  bilinear_8p_f16<<<dim3(B_ * HO_), 512, 0, stream>>>(vh, qh, h16, hbias, (float*)d_out);
}

// Round 5
// 247.330 us; speedup vs baseline: 1.4214x; 1.2407x over previous
//
#include <hip/hip_runtime.h>

// ---------------------------------------------------------------------------
// BCNet: v_=relu(v@Wv^T+bv); q_=relu(q@Wq^T+bq); out[b,h,v,q]=sum_k h[h,k]*v_*q_ + hbias[h]
// Round 5: m97 structure (128x128 tile, BK=64, 4 waves, 32KB LDS, 2-barrier
// loop, 3 blocks/CU) + round-4's verified conflict-free swizzle
// (64B LDS rows [kk][128][32], slot ^= (row>>1)&3, pre-swizzled global src).
// Multi-block/CU restores implicit cross-block MFMA/stage overlap (m114).
// ---------------------------------------------------------------------------

typedef _Float16 h8 __attribute__((ext_vector_type(8)));
typedef float f32x4 __attribute__((ext_vector_type(4)));

#define B_   32
#define NV_  512
#define NQ_  128
#define VD_  2048
#define QD_  1024
#define HK_  1536
#define HO_  8

__device__ __forceinline__ void gload_lds16(const void* g, void* l) {
  __builtin_amdgcn_global_load_lds(
      (const __attribute__((address_space(1))) void*)g,
      (__attribute__((address_space(3))) void*)l, 16, 0, 0);
}

// ---------------------------------------------------------------------------
// Fused f32 -> f16 conversion for all 5 inputs, 8 elems/thread, one launch.
// Unit boundaries (in 8-elem units): v 4194304 | q 524288 | Wv 393216 |
// Wq 196608 | h 1536  => total 5309952 = 20742 * 256 exactly.
// ---------------------------------------------------------------------------
__global__ __launch_bounds__(256) void cvt_all(
    const float* __restrict__ v, const float* __restrict__ q,
    const float* __restrict__ Wv, const float* __restrict__ Wq,
    const float* __restrict__ hm,
    _Float16* __restrict__ v16, _Float16* __restrict__ q16,
    _Float16* __restrict__ Wv16, _Float16* __restrict__ Wq16,
    _Float16* __restrict__ h16) {
  int i = blockIdx.x * blockDim.x + threadIdx.x;
  const float* src;
  _Float16* dst;
  if (i < 4194304)      { src = v;  dst = v16; }
  else if (i < 4718592) { src = q;  dst = q16;  i -= 4194304; }
  else if (i < 5111808) { src = Wv; dst = Wv16; i -= 4718592; }
  else if (i < 5308416) { src = Wq; dst = Wq16; i -= 5111808; }
  else                  { src = hm; dst = h16;  i -= 5308416; }
  const float4* p = (const float4*)src;
  float4 a = p[i * 2], b = p[i * 2 + 1];
  h8 o;
  o[0] = (_Float16)a.x; o[1] = (_Float16)a.y; o[2] = (_Float16)a.z; o[3] = (_Float16)a.w;
  o[4] = (_Float16)b.x; o[5] = (_Float16)b.y; o[6] = (_Float16)b.z; o[7] = (_Float16)b.w;
  ((h8*)dst)[i] = o;
}

// ---------------------------------------------------------------------------
// GEMM: out = relu(A @ Bw^T + bias), f16 in/out. A: MxK, Bw: NxK (K-major).
// 128x128 tile, BK=64 as two [128][32] kk-slabs, 4 waves (2x2), 64x64/wave.
// LDS 32 KB -> 3 blocks/CU (VGPR capped by __launch_bounds__(256,3)).
// Grid: (N/128, M/128).
// ---------------------------------------------------------------------------
template <int KTOT>
__global__ __launch_bounds__(256, 3) void gemm_m97_relu_f16(
    const _Float16* __restrict__ A, const _Float16* __restrict__ Bw,
    const float* __restrict__ bias, _Float16* __restrict__ out, int N) {
  __shared__ __align__(16) _Float16 As[2][128 * 32];
  __shared__ __align__(16) _Float16 Bs[2][128 * 32];

  const int t = threadIdx.x;
  const int lane = t & 63;
  const int wave = t >> 6;
  const int wm = wave >> 1, wn = wave & 1;
  const int bcol = blockIdx.x * 128;
  const int brow = blockIdx.y * 128;

  // staging: thread t -> row t>>2 (0..63), 16B slot t&3; LDS dest linear,
  // global source column pre-swizzled by the involution slot^=(row>>1)&3.
  const int scol = ((t & 3) ^ ((t >> 3) & 3)) * 8;
  const _Float16* Ab = A + (size_t)(brow + (t >> 2)) * KTOT + scol;
  const _Float16* Bb = Bw + (size_t)(bcol + (t >> 2)) * KTOT + scol;

  f32x4 acc[4][4] = {};

  for (int kt = 0; kt < KTOT / 64; ++kt) {
    __syncthreads();  // previous tile's readers done
#pragma unroll
    for (int kk = 0; kk < 2; ++kk) {
      gload_lds16(Ab + kt * 64 + kk * 32, &As[kk][t * 8]);
      gload_lds16(Ab + (size_t)64 * KTOT + kt * 64 + kk * 32, &As[kk][2048 + t * 8]);
      gload_lds16(Bb + kt * 64 + kk * 32, &Bs[kk][t * 8]);
      gload_lds16(Bb + (size_t)64 * KTOT + kt * 64 + kk * 32, &Bs[kk][2048 + t * 8]);
    }
    asm volatile("s_waitcnt vmcnt(0)" ::: "memory");
    __syncthreads();
#pragma unroll
    for (int kk = 0; kk < 2; ++kk) {
      h8 af[4], bf[4];
#pragma unroll
      for (int m = 0; m < 4; ++m) {
        const int row = wm * 64 + m * 16 + (lane & 15);
        af[m] = *(const h8*)&As[kk][row * 32 + ((lane >> 4) ^ ((row >> 1) & 3)) * 8];
      }
#pragma unroll
      for (int n = 0; n < 4; ++n) {
        const int row = wn * 64 + n * 16 + (lane & 15);
        bf[n] = *(const h8*)&Bs[kk][row * 32 + ((lane >> 4) ^ ((row >> 1) & 3)) * 8];
      }
#pragma unroll
      for (int m = 0; m < 4; ++m)
#pragma unroll
        for (int n = 0; n < 4; ++n)
          acc[m][n] = __builtin_amdgcn_mfma_f32_16x16x32_f16(af[m], bf[n], acc[m][n], 0, 0, 0);
    }
  }

#pragma unroll
  for (int m = 0; m < 4; ++m)
#pragma unroll
    for (int n = 0; n < 4; ++n) {
      const int col = bcol + wn * 64 + n * 16 + (lane & 15);
      const float bb = bias[col];
#pragma unroll
      for (int r = 0; r < 4; ++r) {
        const int row = brow + wm * 64 + m * 16 + (lane >> 4) * 4 + r;
        float val = acc[m][n][r] + bb;
        out[(size_t)row * N + col] = (_Float16)(val > 0.f ? val : 0.f);
      }
    }
}

// ---------------------------------------------------------------------------
// Bilinear: out[b,h,v,q] = sum_k vh[b,v,k]*(h16[h,k]*qh[b,q,k]) + hbias[h]
// Same m97 structure. A (vh) via gload_lds; B = qh*h reg-staged with
// swizzled ds_write; h row cached in LDS. Grid: (NV/128, B*HO).
// ---------------------------------------------------------------------------
__global__ __launch_bounds__(256, 3) void bilinear_m97_f16(
    const _Float16* __restrict__ vh, const _Float16* __restrict__ qh,
    const _Float16* __restrict__ h16, const float* __restrict__ hbias,
    float* __restrict__ out) {
  __shared__ __align__(16) _Float16 As[2][128 * 32];
  __shared__ __align__(16) _Float16 Bs[2][128 * 32];
  __shared__ __align__(16) _Float16 hl[HK_];

  const int t = threadIdx.x;
  const int lane = t & 63;
  const int wave = t >> 6;
  const int wm = wave >> 1, wn = wave & 1;
  const int mt = blockIdx.x;   // 0..3
  const int bh = blockIdx.y;   // 0..255
  const int b = bh >> 3, h = bh & 7;

  const int scol = ((t & 3) ^ ((t >> 3) & 3)) * 8;
  const _Float16* Ab = vh + ((size_t)b * NV_ + mt * 128 + (t >> 2)) * HK_ + scol;
  const _Float16* Qb = qh + (size_t)b * NQ_ * HK_;

  // cache the h row (3 KB); consumed after the loop-top __syncthreads()
  for (int i = t; i < HK_ / 8; i += 256)
    *(h8*)&hl[i * 8] = *(const h8*)&h16[(size_t)h * HK_ + i * 8];

  const int qrow = t >> 2;  // 0..63
  const int qs = t & 3;

  f32x4 acc[4][4] = {};

  for (int kt = 0; kt < HK_ / 64; ++kt) {
    __syncthreads();
    // A via direct-to-LDS (pre-swizzled source)
#pragma unroll
    for (int kk = 0; kk < 2; ++kk) {
      gload_lds16(Ab + kt * 64 + kk * 32, &As[kk][t * 8]);
      gload_lds16(Ab + (size_t)64 * HK_ + kt * 64 + kk * 32, &As[kk][2048 + t * 8]);
    }
    // B = qh * h, reg-staged with swizzled ds_write
#pragma unroll
    for (int u = 0; u < 2; ++u) {
      const int row = u * 64 + qrow;
#pragma unroll
      for (int kk = 0; kk < 2; ++kk) {
        const int col = kt * 64 + kk * 32 + qs * 8;
        h8 qv = *(const h8*)&Qb[(size_t)row * HK_ + col];
        h8 hv = *(const h8*)&hl[col];
        *(h8*)&Bs[kk][row * 32 + (qs ^ ((row >> 1) & 3)) * 8] = qv * hv;
      }
    }
    asm volatile("s_waitcnt vmcnt(0)" ::: "memory");
    __syncthreads();
#pragma unroll
    for (int kk = 0; kk < 2; ++kk) {
      h8 af[4], bf[4];
#pragma unroll
      for (int m = 0; m < 4; ++m) {
        const int row = wm * 64 + m * 16 + (lane & 15);
        af[m] = *(const h8*)&As[kk][row * 32 + ((lane >> 4) ^ ((row >> 1) & 3)) * 8];
      }
#pragma unroll
      for (int n = 0; n < 4; ++n) {
        const int row = wn * 64 + n * 16 + (lane & 15);
        bf[n] = *(const h8*)&Bs[kk][row * 32 + ((lane >> 4) ^ ((row >> 1) & 3)) * 8];
      }
#pragma unroll
      for (int m = 0; m < 4; ++m)
#pragma unroll
        for (int n = 0; n < 4; ++n)
          acc[m][n] = __builtin_amdgcn_mfma_f32_16x16x32_f16(af[m], bf[n], acc[m][n], 0, 0, 0);
    }
  }

  const float bb = hbias[h];
  float* O = out + ((size_t)bh * NV_ + (size_t)mt * 128) * NQ_;
#pragma unroll
  for (int m = 0; m < 4; ++m)
#pragma unroll
    for (int n = 0; n < 4; ++n)
#pragma unroll
      for (int r = 0; r < 4; ++r) {
        const int row = wm * 64 + m * 16 + (lane >> 4) * 4 + r;
        const int col = wn * 64 + n * 16 + (lane & 15);
        O[(size_t)row * NQ_ + col] = acc[m][n][r] + bb;
      }
}

// ---------------------------------------------------------------------------
// Workspace layout (bytes): v16@0 (67,108,864) q16@67108864 (8,388,608)
// Wv16@75497472 (6,291,456) Wq16@81788928 (3,145,728) vh@84934656 (50,331,648)
// qh@135266304 (12,582,912) h16@147849216 (24,576) total 147,873,792
// ---------------------------------------------------------------------------
extern "C" void kernel_launch(void* const* d_in, const int* in_sizes, int n_in,
                              void* d_out, int out_size, void* d_ws,
                              size_t ws_size, hipStream_t stream) {
  const float* v = (const float*)d_in[0];
  const float* q = (const float*)d_in[1];
  const float* Wv = (const float*)d_in[2];
  const float* bv = (const float*)d_in[3];
  const float* Wq = (const float*)d_in[4];
  const float* bq = (const float*)d_in[5];
  const float* hmat = (const float*)d_in[6];
  const float* hbias = (const float*)d_in[7];

  if (ws_size < 147873792u) return;

  char* ws = (char*)d_ws;
  _Float16* v16 = (_Float16*)(ws);
  _Float16* q16 = (_Float16*)(ws + 67108864);
  _Float16* Wv16 = (_Float16*)(ws + 75497472);
  _Float16* Wq16 = (_Float16*)(ws + 81788928);
  _Float16* vh = (_Float16*)(ws + 84934656);
  _Float16* qh = (_Float16*)(ws + 135266304);
  _Float16* h16 = (_Float16*)(ws + 147849216);

  cvt_all<<<dim3(20742), 256, 0, stream>>>(v, q, Wv, Wq, hmat,
                                           v16, q16, Wv16, Wq16, h16);

  // v_ = relu(v @ Wv^T + bv): M=16384, N=1536, K=2048 -> grid (12,128)=1536=6*256
  gemm_m97_relu_f16<VD_><<<dim3(HK_ / 128, 16384 / 128), 256, 0, stream>>>(
      v16, Wv16, bv, vh, HK_);
  // q_ = relu(q @ Wq^T + bq): M=4096, N=1536, K=1024 -> grid (12,32)=384 (all resident)
  gemm_m97_relu_f16<QD_><<<dim3(HK_ / 128, 4096 / 128), 256, 0, stream>>>(
      q16, Wq16, bq, qh, HK_);

  // logits: grid (4, 256) = 1024 blocks
  bilinear_m97_f16<<<dim3(NV_ / 128, B_ * HO_), 256, 0, stream>>>(
      vh, qh, h16, hbias, (float*)d_out);
}